// Round 6
// baseline (200.268 us; speedup 1.0000x reference)
//
#include <hip/hip_runtime.h>
#include <cstdint>
#include <cstddef>

// ---------------------------------------------------------------------------
// Flow_24429773980225 — round 6: asymmetric-depth LDS rotation (A:3buf depth-2,
// B:2buf depth-1, 160 KiB exactly), counted vmcnt(12) pipeline, r3 interior.
//   s[r]  = <node_t[r], t[r]> + <x_n[r], uK> + c1,  t = x_n@M1^T + uQ
//   M1    = WQ^T WK,  uQ = WQ^T bK,  uK = WK^T bQ,  c1 = <bQ,bK>
//   dg    = softmax_b(s/128)
//   vw    = x_n@M2^T + bvw,  M2 = WO·WV,  bvw = WO·bV
//   out[r]= <node_t[r], vE> + c0 + sum_c gelu(dg[r]*vw[r,c] + bO[c])·vN[c]
// ---------------------------------------------------------------------------

typedef __attribute__((ext_vector_type(8))) short bfx8;   // 8 bf16
typedef __attribute__((ext_vector_type(4))) short s16x4;  // 4 bf16
typedef __attribute__((ext_vector_type(4))) float f32x4;  // MFMA acc

#define N_SEQ 2048
#define M_TOT 16384   // B*N
#define NT 16         // K / 64

__device__ __forceinline__ unsigned short f2bf(float f) {
  unsigned int u = __float_as_uint(f);
  return (unsigned short)((u + 0x7fffu + ((u >> 16) & 1u)) >> 16);  // RNE
}
__device__ __forceinline__ float bf2f(short s) {
  return __uint_as_float(((unsigned int)(unsigned short)s) << 16);
}
__device__ __forceinline__ float gelu_exact(float g) {
  return 0.5f * g * (1.0f + erff(g * 0.70710678118654752f));
}
__device__ __forceinline__ void gload16(const void* g, void* l) {
  __builtin_amdgcn_global_load_lds(
      (const __attribute__((address_space(1))) unsigned int*)g,
      (__attribute__((address_space(3))) unsigned int*)(unsigned int)(uintptr_t)l,
      16, 0, 0);
}
__device__ __forceinline__ float blk_sum(float v, float* red, int t) {
#pragma unroll
  for (int o = 32; o > 0; o >>= 1) v += __shfl_down(v, o, 64);
  __syncthreads();
  if ((t & 63) == 0) red[t >> 6] = v;
  __syncthreads();
  return red[0] + red[1] + red[2] + red[3];
}

// --------------------------- small precomputes -----------------------------
__global__ __launch_bounds__(256) void colred_kernel(
    const float* __restrict__ WE, const float* __restrict__ WN,
    const float* __restrict__ WQ, const float* __restrict__ WK,
    const float* __restrict__ wa, const float* __restrict__ bQ,
    const float* __restrict__ bK, const float* __restrict__ WEb,
    const float* __restrict__ WNb, const float* __restrict__ WAb,
    float* __restrict__ vE, float* __restrict__ vN,
    float* __restrict__ uQ, float* __restrict__ uK,
    float* __restrict__ c0, float* __restrict__ c1) {
  int y = blockIdx.y;
  if (y < 4) {
    const float* M = y == 0 ? WE : y == 1 ? WN : y == 2 ? WQ : WK;
    const float* wv = (y < 2) ? wa : (y == 2 ? bK : bQ);
    float* dst = y == 0 ? vE : y == 1 ? vN : y == 2 ? uQ : uK;
    int h = blockIdx.x * 256 + threadIdx.x;
    float a = 0.f;
    for (int o = 0; o < 1024; ++o) a += wv[o] * M[(size_t)o * 1024 + h];
    dst[h] = a;
  } else if (blockIdx.x < 2) {
    int t = threadIdx.x;
    float a = 0.f;
    if (blockIdx.x == 0)
      for (int i = t; i < 1024; i += 256) a += wa[i] * (WEb[i] + WNb[i]);
    else
      for (int i = t; i < 1024; i += 256) a += bQ[i] * bK[i];
#pragma unroll
    for (int o = 32; o > 0; o >>= 1) a += __shfl_down(a, o, 64);
    __shared__ float r4[4];
    if ((t & 63) == 0) r4[t >> 6] = a;
    __syncthreads();
    if (t == 0) {
      float tot = r4[0] + r4[1] + r4[2] + r4[3];
      if (blockIdx.x == 0) c0[0] = tot + WAb[0];
      else c1[0] = tot;
    }
  }
}

// bvw[r] = <WO[r,:], bV>
__global__ __launch_bounds__(256) void rowdot_kernel(
    const float* __restrict__ WO, const float* __restrict__ bV,
    float* __restrict__ bvw) {
  int r = blockIdx.x, t = threadIdx.x;
  __shared__ float red[4];
  float4 wv = ((const float4*)(WO + (size_t)r * 1024))[t];
  float4 bv = ((const float4*)bV)[t];
  float a = wv.x * bv.x + wv.y * bv.y + wv.z * bv.z + wv.w * bv.w;
  float tot = blk_sum(a, red, t);
  if (t == 0) bvw[r] = tot;
}

// z 0..2: bf16 TRANSPOSED converts WQ->wqT, WK->wkT, WV->wvT; z==3: WO plain.
__global__ __launch_bounds__(256) void cvt_wT_kernel(
    const float* __restrict__ WQ, const float* __restrict__ WK,
    const float* __restrict__ WV, const float* __restrict__ WO,
    short* __restrict__ wqT, short* __restrict__ wkT,
    short* __restrict__ wvT, short* __restrict__ wo) {
  int bi = blockIdx.x, bj = blockIdx.y, z = blockIdx.z, t = threadIdx.x;
  const float* src = z == 0 ? WQ : z == 1 ? WK : z == 2 ? WV : WO;
  if (z == 3) {
#pragma unroll
    for (int i = 0; i < 16; ++i) {
      int lin = i * 256 + t, r = lin >> 6, c = lin & 63;
      size_t idx = (size_t)(bi * 64 + r) * 1024 + bj * 64 + c;
      wo[idx] = (short)f2bf(src[idx]);
    }
    return;
  }
  __shared__ short tile[64][65];
  short* dst = z == 0 ? wqT : z == 1 ? wkT : wvT;
#pragma unroll
  for (int i = 0; i < 16; ++i) {
    int lin = i * 256 + t, r = lin >> 6, c = lin & 63;
    tile[r][c] = (short)f2bf(src[(size_t)(bi * 64 + r) * 1024 + bj * 64 + c]);
  }
  __syncthreads();
#pragma unroll
  for (int i = 0; i < 16; ++i) {
    int lin = i * 256 + t, r = lin >> 6, c = lin & 63;
    dst[(size_t)(bj * 64 + r) * 1024 + bi * 64 + c] = tile[c][r];
  }
}

// node_next only: xn = bf16(nn), xk[row] = <nn[row], uK>.
__global__ __launch_bounds__(128) void cvt_nn_kernel(
    const float* __restrict__ nn, const float* __restrict__ uK,
    short* __restrict__ xn, float* __restrict__ xk) {
  int row = blockIdx.x, t = threadIdx.x;
  const float* src = nn + (size_t)row * 1024 + t * 8;
  float4 v0 = *(const float4*)src;
  float4 v1 = *(const float4*)(src + 4);
  bfx8 o;
  o[0] = (short)f2bf(v0.x); o[1] = (short)f2bf(v0.y);
  o[2] = (short)f2bf(v0.z); o[3] = (short)f2bf(v0.w);
  o[4] = (short)f2bf(v1.x); o[5] = (short)f2bf(v1.y);
  o[6] = (short)f2bf(v1.z); o[7] = (short)f2bf(v1.w);
  *(bfx8*)(xn + (size_t)row * 1024 + t * 8) = o;
  const float4* uv = (const float4*)(uK + t * 8);
  float4 e0 = uv[0], e1 = uv[1];
  float a = v0.x * e0.x + v0.y * e0.y + v0.z * e0.z + v0.w * e0.w +
            v1.x * e1.x + v1.y * e1.y + v1.z * e1.z + v1.w * e1.w;
#pragma unroll
  for (int off = 32; off > 0; off >>= 1) a += __shfl_down(a, off, 64);
  __shared__ float r2[2];
  if ((t & 63) == 0) r2[t >> 6] = a;
  __syncthreads();
  if (t == 0) xk[row] = r2[0] + r2[1];
}

// M1 = wqT@wkT^T (z=0) and M2 = wo@wvT^T (z=1); 1024^3, 128x128 tiles (m97).
__global__ __launch_bounds__(256) void gemm_pre(
    const short* __restrict__ A0, const short* __restrict__ B0,
    short* __restrict__ D0, const short* __restrict__ A1,
    const short* __restrict__ B1, short* __restrict__ D1) {
  const short* A = blockIdx.z ? A1 : A0;
  const short* B = blockIdx.z ? B1 : B0;
  short* D = blockIdx.z ? D1 : D0;
  __shared__ short sA[128 * 64];
  __shared__ short sB[128 * 64];
  int tid = threadIdx.x, lane = tid & 63, w = tid >> 6;
  int wm = w >> 1, wn = w & 1;
  int bx = blockIdx.x, by = blockIdx.y;
  f32x4 acc[4][4] = {};
  int lrow = lane & 15, lk = (lane >> 4) * 8;
  int srow = lane >> 3, scol = (lane & 7) * 8;
  const short* Ag = A + (size_t)by * 128 * 1024;
  const short* Bg = B + (size_t)bx * 128 * 1024;
  for (int k0 = 0; k0 < 1024; k0 += 64) {
#pragma unroll
    for (int i = 0; i < 4; ++i) {
      int c = w * 4 + i;
      gload16(Ag + (size_t)(c * 8 + srow) * 1024 + k0 + scol, sA + c * 512);
      gload16(Bg + (size_t)(c * 8 + srow) * 1024 + k0 + scol, sB + c * 512);
    }
    __syncthreads();
#pragma unroll
    for (int kk = 0; kk < 64; kk += 32) {
      bfx8 af[4], bfr[4];
#pragma unroll
      for (int mi = 0; mi < 4; ++mi)
        af[mi] = *(const bfx8*)(sA + (wm * 64 + mi * 16 + lrow) * 64 + kk + lk);
#pragma unroll
      for (int nj = 0; nj < 4; ++nj)
        bfr[nj] = *(const bfx8*)(sB + (wn * 64 + nj * 16 + lrow) * 64 + kk + lk);
#pragma unroll
      for (int mi = 0; mi < 4; ++mi)
#pragma unroll
        for (int nj = 0; nj < 4; ++nj)
          acc[mi][nj] = __builtin_amdgcn_mfma_f32_16x16x32_bf16(
              af[mi], bfr[nj], acc[mi][nj], 0, 0, 0);
    }
    __syncthreads();
  }
  int r0 = by * 128 + wm * 64, cb = bx * 128 + wn * 64;
#pragma unroll
  for (int mi = 0; mi < 4; ++mi)
#pragma unroll
    for (int nj = 0; nj < 4; ++nj) {
      int col = cb + nj * 16 + lrow;
#pragma unroll
      for (int r = 0; r < 4; ++r) {
        int row = r0 + mi * 16 + (lane >> 4) * 4 + r;
        D[(size_t)row * 1024 + col] = (short)f2bf(acc[mi][nj][r]);
      }
    }
}

// --------------------- fused main GEMM (256^2, 8 waves) --------------------
// D = xn @ Bf^T, Bf=[M1;M2]. bx<4 -> s+xe partials; bx>=4 -> vw store.
// A: 3 buffers, depth-2 (stage T+2 in body T). B: 2 buffers, depth-1.
// Per-body issue order B(T+1) then A(T+2) -> steady-state vmcnt(12).
__global__ __launch_bounds__(512, 2) void gemm_main(
    const short* __restrict__ A, const short* __restrict__ Bf,
    const float* __restrict__ bias2, const float* __restrict__ nodet,
    const float* __restrict__ vE, float* __restrict__ sPart,
    float* __restrict__ xePart, short* __restrict__ vw) {
  __shared__ short sA[3][16384];  // 96 KiB
  __shared__ short sB[2][16384];  // 64 KiB  (total = 160 KiB exactly)
  int tid = threadIdx.x;
  int lane = tid & 63, w = tid >> 6;   // 8 waves
  int wm = w >> 2, wn = w & 3;         // 2 x 4 wave grid
  int wg = blockIdx.x;
  int work = (wg & 7) * 64 + (wg >> 3);  // XCD-chunked, bijective (512%8==0)
  int by = work >> 3, bx = work & 7;
  int lrow = lane & 15, g = lane >> 4;
  int sw0 = g ^ (lrow & 7);            // swizzled slot, kk=0 half
  int sg = (lane & 7) ^ (lane >> 3);   // inverse-swizzled global col slot
  const short* Agt = A + ((size_t)(by * 256 + w * 32 + (lane >> 3))) * 1024 + sg * 8;
  const short* Bgt = Bf + ((size_t)(bx * 256 + w * 32 + (lane >> 3))) * 1024 + sg * 8;

  f32x4 acc[8][4] = {};

  auto stageA = [&](int b, int kt) {
#pragma unroll
    for (int i = 0; i < 4; ++i)
      gload16(Agt + kt * 64 + i * 8192, &sA[b][w * 2048 + i * 512]);
  };
  auto stageB = [&](int b, int kt) {
#pragma unroll
    for (int i = 0; i < 4; ++i)
      gload16(Bgt + kt * 64 + i * 8192, &sB[b][w * 2048 + i * 512]);
  };

  // prologue: A(0), B(0), A(1)   (12 issues in flight)
  stageA(0, 0);
  stageB(0, 0);
  stageA(1, 1);

  int arow = wm * 128 + lrow, brow = wn * 64 + lrow;
  for (int kt = 0; kt < NT; ++kt) {
    // body stages: B(kt+1) then A(kt+2)
    if (kt + 1 < NT) stageB((kt + 1) & 1, kt + 1);
    if (kt + 2 < NT) stageA((kt + 2) % 3, kt + 2);
    // opening wait: A(kt), B(kt) resident; later groups stay in flight
    if (kt < NT - 2)       asm volatile("s_waitcnt vmcnt(12)" ::: "memory");
    else if (kt == NT - 2) asm volatile("s_waitcnt vmcnt(8)" ::: "memory");
    else                   asm volatile("s_waitcnt vmcnt(0)" ::: "memory");
    __builtin_amdgcn_sched_barrier(0);
    __builtin_amdgcn_s_barrier();
    __builtin_amdgcn_sched_barrier(0);

    const short* sa = &sA[kt % 3][0];
    const short* sb = &sB[kt & 1][0];
    bfx8 bq[4][2];
#pragma unroll
    for (int nj = 0; nj < 4; ++nj) {
      bq[nj][0] = *(const bfx8*)(sb + (brow + nj * 16) * 64 + sw0 * 8);
      bq[nj][1] = *(const bfx8*)(sb + (brow + nj * 16) * 64 + (sw0 ^ 4) * 8);
    }
#pragma unroll
    for (int q = 0; q < 4; ++q) {  // 4 quadrant runs of 16 MFMA (r3 interior)
      bfx8 a0 = *(const bfx8*)(sa + (arow + (2 * q) * 16) * 64 + sw0 * 8);
      bfx8 a1 = *(const bfx8*)(sa + (arow + (2 * q) * 16) * 64 + (sw0 ^ 4) * 8);
      bfx8 a2 = *(const bfx8*)(sa + (arow + (2 * q + 1) * 16) * 64 + sw0 * 8);
      bfx8 a3 = *(const bfx8*)(sa + (arow + (2 * q + 1) * 16) * 64 + (sw0 ^ 4) * 8);
      __builtin_amdgcn_s_setprio(1);
#pragma unroll
      for (int nj = 0; nj < 4; ++nj) {
        acc[2 * q][nj] = __builtin_amdgcn_mfma_f32_16x16x32_bf16(
            a0, bq[nj][0], acc[2 * q][nj], 0, 0, 0);
        acc[2 * q][nj] = __builtin_amdgcn_mfma_f32_16x16x32_bf16(
            a1, bq[nj][1], acc[2 * q][nj], 0, 0, 0);
        acc[2 * q + 1][nj] = __builtin_amdgcn_mfma_f32_16x16x32_bf16(
            a2, bq[nj][0], acc[2 * q + 1][nj], 0, 0, 0);
        acc[2 * q + 1][nj] = __builtin_amdgcn_mfma_f32_16x16x32_bf16(
            a3, bq[nj][1], acc[2 * q + 1][nj], 0, 0, 0);
      }
      __builtin_amdgcn_s_setprio(0);
    }
    __builtin_amdgcn_sched_barrier(0);
    __builtin_amdgcn_s_barrier();      // all reads of tile kt done
    __builtin_amdgcn_sched_barrier(0);
  }

  int row0 = by * 256 + wm * 128;
  int cb = bx * 256 + wn * 64;  // column base in [0,2048)
  if (bx < 4) {
    // t-half: per-row 64-col partials of <node_t, t+uQ> AND <node_t, vE>
    float bias_nj[4], ve_nj[4];
#pragma unroll
    for (int nj = 0; nj < 4; ++nj) {
      bias_nj[nj] = bias2[cb + nj * 16 + lrow];
      ve_nj[nj] = vE[cb + nj * 16 + lrow];
    }
    int px = bx * 4 + wn;  // 16 partials per row
#pragma unroll
    for (int mi = 0; mi < 8; ++mi) {
#pragma unroll
      for (int r = 0; r < 4; ++r) {
        int row = row0 + mi * 16 + g * 4 + r;
        const float* xr = nodet + (size_t)row * 1024;
        float v = 0.f, v2 = 0.f;
#pragma unroll
        for (int nj = 0; nj < 4; ++nj) {
          float xv = xr[cb + nj * 16 + lrow];
          v += (acc[mi][nj][r] + bias_nj[nj]) * xv;
          v2 += ve_nj[nj] * xv;
        }
        v += __shfl_xor(v, 1, 64);   v2 += __shfl_xor(v2, 1, 64);
        v += __shfl_xor(v, 2, 64);   v2 += __shfl_xor(v2, 2, 64);
        v += __shfl_xor(v, 4, 64);   v2 += __shfl_xor(v2, 4, 64);
        v += __shfl_xor(v, 8, 64);   v2 += __shfl_xor(v2, 8, 64);
        if (lrow == 0) {
          sPart[(size_t)row * 16 + px] = v;
          xePart[(size_t)row * 16 + px] = v2;
        }
      }
    }
  } else {
#pragma unroll
    for (int mi = 0; mi < 8; ++mi)
#pragma unroll
      for (int nj = 0; nj < 4; ++nj) {
        int colv = cb - 1024 + nj * 16 + lrow;
        float bv = bias2[1024 + colv];
#pragma unroll
        for (int r = 0; r < 4; ++r) {
          int row = row0 + mi * 16 + g * 4 + r;
          vw[(size_t)row * 1024 + colv] = (short)f2bf(acc[mi][nj][r] + bv);
        }
      }
  }
}

// Per n: s[b] = sum_16 sPart + xk + c1; dg = softmax_b(s/128). 64 threads.
__global__ __launch_bounds__(64) void sdiag_kernel(
    const float* __restrict__ sPart, const float* __restrict__ xk,
    const float* __restrict__ c1p, float* __restrict__ dg) {
  int n = blockIdx.x, lane = threadIdx.x;
  int b = lane >> 3, j = lane & 7;
  size_t row = (size_t)b * N_SEQ + n;
  float v = sPart[row * 16 + j * 2] + sPart[row * 16 + j * 2 + 1];
  v += __shfl_xor(v, 1, 64);
  v += __shfl_xor(v, 2, 64);
  v += __shfl_xor(v, 4, 64);
  float s = v + xk[row] + c1p[0];
  float m = s;
  m = fmaxf(m, __shfl_xor(m, 8, 64));
  m = fmaxf(m, __shfl_xor(m, 16, 64));
  m = fmaxf(m, __shfl_xor(m, 32, 64));
  float e = expf((s - m) * (1.0f / 128.0f));
  float sum = e;
  sum += __shfl_xor(sum, 8, 64);
  sum += __shfl_xor(sum, 16, 64);
  sum += __shfl_xor(sum, 32, 64);
  if (j == 0) dg[row] = e / sum;
}

// out[row] = xe[row] + c0 + sum_c gelu(dg*vw[row,c] + bO[c]) * vN[c]
__global__ __launch_bounds__(256) void out_kernel(
    const short* __restrict__ vw, const float* __restrict__ dg,
    const float* __restrict__ xePart, const float* __restrict__ vN,
    const float* __restrict__ bO, const float* __restrict__ c0p,
    float* __restrict__ out) {
  int n = blockIdx.x, t = threadIdx.x;
  __shared__ float red[4];
  __shared__ float xeS[8];
  if (t < 128) {   // gather xe: 8 rows x 16 partials, waves 0-1
    int b = t >> 4, j = t & 15;
    float p = xePart[((size_t)b * N_SEQ + n) * 16 + j];
    p += __shfl_xor(p, 1, 64);
    p += __shfl_xor(p, 2, 64);
    p += __shfl_xor(p, 4, 64);
    p += __shfl_xor(p, 8, 64);
    if (j == 0) xeS[b] = p;
  }
  __syncthreads();
  float4 bo = ((const float4*)bO)[t];
  float4 vn = ((const float4*)vN)[t];
  float c0 = c0p[0];
#pragma unroll
  for (int b = 0; b < 8; ++b) {
    size_t row = (size_t)b * N_SEQ + n;
    float d = dg[row];
    s16x4 vv = *(const s16x4*)(vw + row * 1024 + t * 4);
    float gx, a = 0.f;
    gx = fmaf(d, bf2f(vv[0]), bo.x); a += gelu_exact(gx) * vn.x;
    gx = fmaf(d, bf2f(vv[1]), bo.y); a += gelu_exact(gx) * vn.y;
    gx = fmaf(d, bf2f(vv[2]), bo.z); a += gelu_exact(gx) * vn.z;
    gx = fmaf(d, bf2f(vv[3]), bo.w); a += gelu_exact(gx) * vn.w;
    float tot = blk_sum(a, red, t);
    if (t == 0) out[row] = xeS[b] + c0 + tot;
  }
}

// ---------------------------------------------------------------------------
extern "C" void kernel_launch(void* const* d_in, const int* in_sizes, int n_in,
                              void* d_out, int out_size, void* d_ws,
                              size_t ws_size, hipStream_t stream) {
  const float* nt  = (const float*)d_in[0];
  const float* nn  = (const float*)d_in[1];
  const float* WQ  = (const float*)d_in[2];
  const float* bQ  = (const float*)d_in[3];
  const float* WK  = (const float*)d_in[4];
  const float* bK  = (const float*)d_in[5];
  const float* WV  = (const float*)d_in[6];
  const float* bV  = (const float*)d_in[7];
  const float* WO  = (const float*)d_in[8];
  const float* bO  = (const float*)d_in[9];
  const float* WE  = (const float*)d_in[10];
  const float* WEb = (const float*)d_in[11];
  const float* WN  = (const float*)d_in[12];
  const float* WNb = (const float*)d_in[13];
  const float* wa  = (const float*)d_in[14];
  const float* WAb = (const float*)d_in[15];
  float* out = (float*)d_out;

  char* w = (char*)d_ws;
  size_t o = 0;
  const size_t BIG = (size_t)M_TOT * 1024 * 2;          // 33.55 MB
  short* xn     = (short*)(w + o); o += BIG;
  short* vw     = (short*)(w + o); o += BIG;
  short* Bf     = (short*)(w + o); o += (size_t)2048 * 1024 * 2;  // [M1;M2]
  short* wqT    = (short*)(w + o); o += 2097152;
  short* wkT    = (short*)(w + o); o += 2097152;
  short* wvT    = (short*)(w + o); o += 2097152;
  short* wo     = (short*)(w + o); o += 2097152;
  float* sPart  = (float*)(w + o); o += (size_t)M_TOT * 16 * 4;   // 1 MB
  float* xePart = (float*)(w + o); o += (size_t)M_TOT * 16 * 4;   // 1 MB
  float* bias2  = (float*)(w + o); o += 8192;           // [uQ(1024); bvw(1024)]
  float* vE     = (float*)(w + o); o += 4096;
  float* vN     = (float*)(w + o); o += 4096;
  float* uK     = (float*)(w + o); o += 4096;
  float* xk     = (float*)(w + o); o += 65536;
  float* dg     = (float*)(w + o); o += 65536;
  float* c0     = (float*)(w + o); o += 256;
  float* c1     = (float*)(w + o); o += 256;
  (void)ws_size; (void)in_sizes; (void)n_in; (void)out_size;

  cvt_wT_kernel<<<dim3(16, 16, 4), 256, 0, stream>>>(WQ, WK, WV, WO,
                                                     wqT, wkT, wvT, wo);
  colred_kernel<<<dim3(4, 5), 256, 0, stream>>>(WE, WN, WQ, WK, wa, bQ, bK,
                                                WEb, WNb, WAb, vE, vN,
                                                bias2, uK, c0, c1);
  rowdot_kernel<<<1024, 256, 0, stream>>>(WO, bV, bias2 + 1024);
  cvt_nn_kernel<<<M_TOT, 128, 0, stream>>>(nn, uK, xn, xk);
  gemm_pre<<<dim3(8, 8, 2), 256, 0, stream>>>(wqT, wkT, Bf,
                                              wo, wvT, Bf + 1048576);
  gemm_main<<<512, 512, 0, stream>>>(xn, Bf, bias2, nt, vE,
                                     sPart, xePart, vw);
  sdiag_kernel<<<N_SEQ, 64, 0, stream>>>(sPart, xk, c1, dg);
  out_kernel<<<N_SEQ, 256, 0, stream>>>(vw, dg, xePart, vN, bO, c0, out);
}

// Round 7
// 162.770 us; speedup vs baseline: 1.2304x; 1.2304x over previous
//
#include <hip/hip_runtime.h>
#include <cstdint>
#include <cstddef>

// ---------------------------------------------------------------------------
// Flow_24429773980225 — round 7: r3 GEMM pipeline (proven 92us) + 4-launch
// pipeline: prep_w -> prep2 (gemm_pre || cvt_nn) -> gemm_main -> out2.
//   s[r]  = <node_t[r], t[r]> + <x_n[r], uK> + c1,  t = x_n@M1^T + uQ
//   M1    = WQ^T WK,  uQ = WQ^T bK,  uK = WK^T bQ,  c1 = <bQ,bK>
//   dg    = softmax_b(s/128)
//   vw    = x_n@M2^T + bvw,  M2 = WO·WV,  bvw = WO·bV
//   out[r]= <node_t[r], vE> + c0 + sum_c gelu(dg[r]*vw[r,c] + bO[c])·vN[c]
// ---------------------------------------------------------------------------

typedef __attribute__((ext_vector_type(8))) short bfx8;   // 8 bf16
typedef __attribute__((ext_vector_type(4))) short s16x4;  // 4 bf16
typedef __attribute__((ext_vector_type(4))) float f32x4;  // MFMA acc

#define N_SEQ 2048
#define M_TOT 16384   // B*N
#define NT 16         // K / 64

__device__ __forceinline__ unsigned short f2bf(float f) {
  unsigned int u = __float_as_uint(f);
  return (unsigned short)((u + 0x7fffu + ((u >> 16) & 1u)) >> 16);  // RNE
}
__device__ __forceinline__ float bf2f(short s) {
  return __uint_as_float(((unsigned int)(unsigned short)s) << 16);
}
__device__ __forceinline__ float gelu_exact(float g) {
  return 0.5f * g * (1.0f + erff(g * 0.70710678118654752f));
}
__device__ __forceinline__ void gload16(const void* g, void* l) {
  __builtin_amdgcn_global_load_lds(
      (const __attribute__((address_space(1))) unsigned int*)g,
      (__attribute__((address_space(3))) unsigned int*)(unsigned int)(uintptr_t)l,
      16, 0, 0);
}

// ------------------- prep_w: weights pass (one launch) ---------------------
// bid 0..1023   : cvt_wT  (z=bid>>8: 0 WQ^T,1 WK^T,2 WV^T,3 WO plain)
// bid 1024..1039: colred  y=(bid-1024)>>2 (vE,vN,uQ,uK), x=(bid-1024)&3
// bid 1040..1041: c0 / c1 scalars
// bid 1042..2065: rowdot  bvw[r] = <WO[r,:], bV>
__global__ __launch_bounds__(256) void prep_w(
    const float* __restrict__ WQ, const float* __restrict__ WK,
    const float* __restrict__ WV, const float* __restrict__ WO,
    const float* __restrict__ WE, const float* __restrict__ WN,
    const float* __restrict__ wa, const float* __restrict__ bQ,
    const float* __restrict__ bK, const float* __restrict__ bV,
    const float* __restrict__ WEb, const float* __restrict__ WNb,
    const float* __restrict__ WAb,
    short* __restrict__ wqT, short* __restrict__ wkT,
    short* __restrict__ wvT, short* __restrict__ wo_bf,
    float* __restrict__ vE, float* __restrict__ vN,
    float* __restrict__ uQ, float* __restrict__ uK,
    float* __restrict__ c0, float* __restrict__ c1,
    float* __restrict__ bvw) {
  __shared__ short tile[64][65];
  __shared__ float redw[4];
  int bid = blockIdx.x, t = threadIdx.x;
  if (bid < 1024) {
    int z = bid >> 8, idx = bid & 255, bi = idx >> 4, bj = idx & 15;
    const float* src = z == 0 ? WQ : z == 1 ? WK : z == 2 ? WV : WO;
    if (z == 3) {
#pragma unroll
      for (int i = 0; i < 16; ++i) {
        int lin = i * 256 + t, r = lin >> 6, c = lin & 63;
        size_t idx2 = (size_t)(bi * 64 + r) * 1024 + bj * 64 + c;
        wo_bf[idx2] = (short)f2bf(src[idx2]);
      }
      return;
    }
    short* dst = z == 0 ? wqT : z == 1 ? wkT : wvT;
#pragma unroll
    for (int i = 0; i < 16; ++i) {
      int lin = i * 256 + t, r = lin >> 6, c = lin & 63;
      tile[r][c] = (short)f2bf(src[(size_t)(bi * 64 + r) * 1024 + bj * 64 + c]);
    }
    __syncthreads();
#pragma unroll
    for (int i = 0; i < 16; ++i) {
      int lin = i * 256 + t, r = lin >> 6, c = lin & 63;
      dst[(size_t)(bj * 64 + r) * 1024 + bi * 64 + c] = tile[c][r];
    }
  } else if (bid < 1040) {
    int y = (bid - 1024) >> 2, bx = (bid - 1024) & 3;
    const float* M = y == 0 ? WE : y == 1 ? WN : y == 2 ? WQ : WK;
    const float* wv = (y < 2) ? wa : (y == 2 ? bK : bQ);
    float* dst = y == 0 ? vE : y == 1 ? vN : y == 2 ? uQ : uK;
    int h = bx * 256 + t;
    float a = 0.f;
    for (int o = 0; o < 1024; ++o) a += wv[o] * M[(size_t)o * 1024 + h];
    dst[h] = a;
  } else if (bid < 1042) {
    int which = bid - 1040;
    float a = 0.f;
    if (which == 0)
      for (int i = t; i < 1024; i += 256) a += wa[i] * (WEb[i] + WNb[i]);
    else
      for (int i = t; i < 1024; i += 256) a += bQ[i] * bK[i];
#pragma unroll
    for (int o = 32; o > 0; o >>= 1) a += __shfl_down(a, o, 64);
    if ((t & 63) == 0) redw[t >> 6] = a;
    __syncthreads();
    if (t == 0) {
      float tot = redw[0] + redw[1] + redw[2] + redw[3];
      if (which == 0) c0[0] = tot + WAb[0];
      else c1[0] = tot;
    }
  } else {
    int r = bid - 1042;
    float4 wv = ((const float4*)(WO + (size_t)r * 1024))[t];
    float4 bv = ((const float4*)bV)[t];
    float a = wv.x * bv.x + wv.y * bv.y + wv.z * bv.z + wv.w * bv.w;
#pragma unroll
    for (int o = 32; o > 0; o >>= 1) a += __shfl_down(a, o, 64);
    if ((t & 63) == 0) redw[t >> 6] = a;
    __syncthreads();
    if (t == 0) bvw[r] = redw[0] + redw[1] + redw[2] + redw[3];
  }
}

// --------- prep2: gemm_pre (128 blocks) || cvt_nn (8192 blocks) ------------
// bid<128: M1 = wqT@wkT^T (z=0), M2 = wo@wvT^T (z=1); 128x128 tiles.
// bid>=128: rows 2*(bid-128)+{0,1}: xn = bf16(nn), xk = <nn, uK>.
__global__ __launch_bounds__(256) void prep2(
    const short* __restrict__ wqT, const short* __restrict__ wkT,
    const short* __restrict__ wvT, const short* __restrict__ wo_bf,
    short* __restrict__ M1, short* __restrict__ M2,
    const float* __restrict__ nn, const float* __restrict__ uK,
    short* __restrict__ xn, float* __restrict__ xk) {
  __shared__ short sA[128 * 64];
  __shared__ short sB[128 * 64];
  __shared__ float red4[4];
  int bid = blockIdx.x, tid = threadIdx.x;
  if (bid >= 128) {
    int cb = bid - 128;
    int half = tid >> 7, tl = tid & 127;
    int row = cb * 2 + half;
    const float* src = nn + (size_t)row * 1024 + tl * 8;
    float4 v0 = *(const float4*)src;
    float4 v1 = *(const float4*)(src + 4);
    bfx8 o;
    o[0] = (short)f2bf(v0.x); o[1] = (short)f2bf(v0.y);
    o[2] = (short)f2bf(v0.z); o[3] = (short)f2bf(v0.w);
    o[4] = (short)f2bf(v1.x); o[5] = (short)f2bf(v1.y);
    o[6] = (short)f2bf(v1.z); o[7] = (short)f2bf(v1.w);
    *(bfx8*)(xn + (size_t)row * 1024 + tl * 8) = o;
    const float4* uv = (const float4*)(uK + tl * 8);
    float4 e0 = uv[0], e1 = uv[1];
    float a = v0.x * e0.x + v0.y * e0.y + v0.z * e0.z + v0.w * e0.w +
              v1.x * e1.x + v1.y * e1.y + v1.z * e1.z + v1.w * e1.w;
#pragma unroll
    for (int off = 32; off > 0; off >>= 1) a += __shfl_down(a, off, 64);
    if ((tid & 63) == 0) red4[tid >> 6] = a;
    __syncthreads();
    if (tl == 0) xk[row] = red4[half * 2] + red4[half * 2 + 1];
    return;
  }
  int z = bid >> 6, by = (bid >> 3) & 7, bx = bid & 7;
  const short* A = z ? wo_bf : wqT;
  const short* B = z ? wvT : wkT;
  short* D = z ? M2 : M1;
  int lane = tid & 63, w = tid >> 6;
  int wm = w >> 1, wn = w & 1;
  f32x4 acc[4][4] = {};
  int lrow = lane & 15, lk = (lane >> 4) * 8;
  int srow = lane >> 3, scol = (lane & 7) * 8;
  const short* Ag = A + (size_t)by * 128 * 1024;
  const short* Bg = B + (size_t)bx * 128 * 1024;
  for (int k0 = 0; k0 < 1024; k0 += 64) {
#pragma unroll
    for (int i = 0; i < 4; ++i) {
      int c = w * 4 + i;
      gload16(Ag + (size_t)(c * 8 + srow) * 1024 + k0 + scol, sA + c * 512);
      gload16(Bg + (size_t)(c * 8 + srow) * 1024 + k0 + scol, sB + c * 512);
    }
    __syncthreads();
#pragma unroll
    for (int kk = 0; kk < 64; kk += 32) {
      bfx8 af[4], bfr[4];
#pragma unroll
      for (int mi = 0; mi < 4; ++mi)
        af[mi] = *(const bfx8*)(sA + (wm * 64 + mi * 16 + lrow) * 64 + kk + lk);
#pragma unroll
      for (int nj = 0; nj < 4; ++nj)
        bfr[nj] = *(const bfx8*)(sB + (wn * 64 + nj * 16 + lrow) * 64 + kk + lk);
#pragma unroll
      for (int mi = 0; mi < 4; ++mi)
#pragma unroll
        for (int nj = 0; nj < 4; ++nj)
          acc[mi][nj] = __builtin_amdgcn_mfma_f32_16x16x32_bf16(
              af[mi], bfr[nj], acc[mi][nj], 0, 0, 0);
    }
    __syncthreads();
  }
  int r0 = by * 128 + wm * 64, cb2 = bx * 128 + wn * 64;
#pragma unroll
  for (int mi = 0; mi < 4; ++mi)
#pragma unroll
    for (int nj = 0; nj < 4; ++nj) {
      int col = cb2 + nj * 16 + lrow;
#pragma unroll
      for (int r = 0; r < 4; ++r) {
        int row = r0 + mi * 16 + (lane >> 4) * 4 + r;
        D[(size_t)row * 1024 + col] = (short)f2bf(acc[mi][nj][r]);
      }
    }
}

// --------------------- fused main GEMM (256^2, 8 waves) --------------------
// Exact r3 pipeline (proven 92us): 2 LDS bufs, stage-all-at-top, vmcnt(8),
// 2 barriers/tile, B-preload + 4 quadrant runs of 16 MFMA + setprio.
// Epilogue: bx<4 -> s+xe partials (node_t read once); bx>=4 -> vw store.
__global__ __launch_bounds__(512, 2) void gemm_main(
    const short* __restrict__ A, const short* __restrict__ Bf,
    const float* __restrict__ bias2, const float* __restrict__ nodet,
    const float* __restrict__ vE, float* __restrict__ sPart,
    float* __restrict__ xePart, short* __restrict__ vw) {
  __shared__ short sA[2][16384];  // [buf][256 rows x 64 cols], XOR-swizzled
  __shared__ short sB[2][16384];
  int tid = threadIdx.x;
  int lane = tid & 63, w = tid >> 6;   // 8 waves
  int wm = w >> 2, wn = w & 3;         // 2 x 4 wave grid
  int wg = blockIdx.x;
  int work = (wg & 7) * 64 + (wg >> 3);  // XCD-chunked, bijective (512%8==0)
  int by = work >> 3, bx = work & 7;
  int lrow = lane & 15, g = lane >> 4;
  int sw0 = g ^ (lrow & 7);            // swizzled slot, kk=0 half
  int sg = (lane & 7) ^ (lane >> 3);   // inverse-swizzled global col slot
  const short* Agt = A + ((size_t)(by * 256 + w * 32 + (lane >> 3))) * 1024 + sg * 8;
  const short* Bgt = Bf + ((size_t)(bx * 256 + w * 32 + (lane >> 3))) * 1024 + sg * 8;

  f32x4 acc[8][4] = {};

  auto stage = [&](int buf, int kt) {
    const short* ag = Agt + kt * 64;
    const short* bg = Bgt + kt * 64;
    short* la = &sA[buf][w * 2048];
    short* lb = &sB[buf][w * 2048];
#pragma unroll
    for (int i = 0; i < 4; ++i) {
      gload16(ag + i * 8192, la + i * 512);
      gload16(bg + i * 8192, lb + i * 512);
    }
  };

  stage(0, 0);
  int cur = 0;
  int arow = wm * 128 + lrow, brow = wn * 64 + lrow;
  for (int kt = 0; kt < NT; ++kt) {
    if (kt + 1 < NT) {
      stage(cur ^ 1, kt + 1);
      asm volatile("s_waitcnt vmcnt(8)" ::: "memory");  // own 8 for buf[cur] done
    } else {
      asm volatile("s_waitcnt vmcnt(0)" ::: "memory");
    }
    __builtin_amdgcn_sched_barrier(0);
    __builtin_amdgcn_s_barrier();      // everyone's buf[cur] loads visible
    __builtin_amdgcn_sched_barrier(0);

    const short* sa = &sA[cur][0];
    const short* sb = &sB[cur][0];
    bfx8 bq[4][2];
#pragma unroll
    for (int nj = 0; nj < 4; ++nj) {
      bq[nj][0] = *(const bfx8*)(sb + (brow + nj * 16) * 64 + sw0 * 8);
      bq[nj][1] = *(const bfx8*)(sb + (brow + nj * 16) * 64 + (sw0 ^ 4) * 8);
    }
#pragma unroll
    for (int q = 0; q < 4; ++q) {  // 4 quadrant runs x 16 MFMA
      bfx8 a0 = *(const bfx8*)(sa + (arow + (2 * q) * 16) * 64 + sw0 * 8);
      bfx8 a1 = *(const bfx8*)(sa + (arow + (2 * q) * 16) * 64 + (sw0 ^ 4) * 8);
      bfx8 a2 = *(const bfx8*)(sa + (arow + (2 * q + 1) * 16) * 64 + sw0 * 8);
      bfx8 a3 = *(const bfx8*)(sa + (arow + (2 * q + 1) * 16) * 64 + (sw0 ^ 4) * 8);
      __builtin_amdgcn_s_setprio(1);
#pragma unroll
      for (int nj = 0; nj < 4; ++nj) {
        acc[2 * q][nj] = __builtin_amdgcn_mfma_f32_16x16x32_bf16(
            a0, bq[nj][0], acc[2 * q][nj], 0, 0, 0);
        acc[2 * q][nj] = __builtin_amdgcn_mfma_f32_16x16x32_bf16(
            a1, bq[nj][1], acc[2 * q][nj], 0, 0, 0);
        acc[2 * q + 1][nj] = __builtin_amdgcn_mfma_f32_16x16x32_bf16(
            a2, bq[nj][0], acc[2 * q + 1][nj], 0, 0, 0);
        acc[2 * q + 1][nj] = __builtin_amdgcn_mfma_f32_16x16x32_bf16(
            a3, bq[nj][1], acc[2 * q + 1][nj], 0, 0, 0);
      }
      __builtin_amdgcn_s_setprio(0);
    }
    __builtin_amdgcn_sched_barrier(0);
    __builtin_amdgcn_s_barrier();      // all reads of buf[cur] done
    __builtin_amdgcn_sched_barrier(0);
    cur ^= 1;
  }

  int row0 = by * 256 + wm * 128;
  int cb = bx * 256 + wn * 64;  // column base in [0,2048)
  if (bx < 4) {
    // t-half: per-row 64-col partials of <node_t, t+uQ> AND <node_t, vE>
    float bias_nj[4], ve_nj[4];
#pragma unroll
    for (int nj = 0; nj < 4; ++nj) {
      bias_nj[nj] = bias2[cb + nj * 16 + lrow];
      ve_nj[nj] = vE[cb + nj * 16 + lrow];
    }
    int px = bx * 4 + wn;  // 16 partials per row
#pragma unroll
    for (int mi = 0; mi < 8; ++mi) {
#pragma unroll
      for (int r = 0; r < 4; ++r) {
        int row = row0 + mi * 16 + g * 4 + r;
        const float* xr = nodet + (size_t)row * 1024;
        float v = 0.f, v2 = 0.f;
#pragma unroll
        for (int nj = 0; nj < 4; ++nj) {
          float xv = xr[cb + nj * 16 + lrow];
          v += (acc[mi][nj][r] + bias_nj[nj]) * xv;
          v2 += ve_nj[nj] * xv;
        }
        v += __shfl_xor(v, 1, 64);   v2 += __shfl_xor(v2, 1, 64);
        v += __shfl_xor(v, 2, 64);   v2 += __shfl_xor(v2, 2, 64);
        v += __shfl_xor(v, 4, 64);   v2 += __shfl_xor(v2, 4, 64);
        v += __shfl_xor(v, 8, 64);   v2 += __shfl_xor(v2, 8, 64);
        if (lrow == 0) {
          sPart[(size_t)row * 16 + px] = v;
          xePart[(size_t)row * 16 + px] = v2;
        }
      }
    }
  } else {
#pragma unroll
    for (int mi = 0; mi < 8; ++mi)
#pragma unroll
      for (int nj = 0; nj < 4; ++nj) {
        int colv = cb - 1024 + nj * 16 + lrow;
        float bv = bias2[1024 + colv];
#pragma unroll
        for (int r = 0; r < 4; ++r) {
          int row = row0 + mi * 16 + g * 4 + r;
          vw[(size_t)row * 1024 + colv] = (short)f2bf(acc[mi][nj][r] + bv);
        }
      }
  }
}

// --------------- out2: sdiag + gelu-sum fused (per n, 256 thr) -------------
// Phase 1 (t<128): s[b] = sum_16 sPart + xk + c1; xe[b] = sum_16 xePart.
// Phase 2: dg = softmax_b(s/128) (redundant per-thread from LDS).
// Phase 3: out[row] = xe[b] + c0 + sum_c gelu(dg*vw[row,c]+bO[c])*vN[c].
__global__ __launch_bounds__(256) void out2_kernel(
    const short* __restrict__ vw, const float* __restrict__ sPart,
    const float* __restrict__ xePart, const float* __restrict__ xk,
    const float* __restrict__ vN, const float* __restrict__ bO,
    const float* __restrict__ c0p, const float* __restrict__ c1p,
    float* __restrict__ out) {
  int n = blockIdx.x, t = threadIdx.x;
  __shared__ float red[4];
  __shared__ float sS[8], xeS[8];
  if (t < 128) {
    int b = t >> 4, j = t & 15;
    size_t row = (size_t)b * N_SEQ + n;
    float p = sPart[row * 16 + j];
    float q = xePart[row * 16 + j];
    p += __shfl_xor(p, 1, 64);  q += __shfl_xor(q, 1, 64);
    p += __shfl_xor(p, 2, 64);  q += __shfl_xor(q, 2, 64);
    p += __shfl_xor(p, 4, 64);  q += __shfl_xor(q, 4, 64);
    p += __shfl_xor(p, 8, 64);  q += __shfl_xor(q, 8, 64);
    if (j == 0) {
      sS[b] = p + xk[row] + c1p[0];
      xeS[b] = q;
    }
  }
  __syncthreads();
  // 8-way softmax (each thread redundantly)
  float sv[8], dgv[8];
#pragma unroll
  for (int b = 0; b < 8; ++b) sv[b] = sS[b];
  float m = sv[0];
#pragma unroll
  for (int b = 1; b < 8; ++b) m = fmaxf(m, sv[b]);
  float sum = 0.f;
#pragma unroll
  for (int b = 0; b < 8; ++b) { dgv[b] = expf((sv[b] - m) * (1.0f / 128.0f)); sum += dgv[b]; }
  float inv = 1.0f / sum;
  float4 bo = ((const float4*)bO)[t];
  float4 vn = ((const float4*)vN)[t];
  float c0 = c0p[0];
#pragma unroll
  for (int b = 0; b < 8; ++b) {
    size_t row = (size_t)b * N_SEQ + n;
    float d = dgv[b] * inv;
    s16x4 vv = *(const s16x4*)(vw + row * 1024 + t * 4);
    float gx, a = 0.f;
    gx = fmaf(d, bf2f(vv[0]), bo.x); a += gelu_exact(gx) * vn.x;
    gx = fmaf(d, bf2f(vv[1]), bo.y); a += gelu_exact(gx) * vn.y;
    gx = fmaf(d, bf2f(vv[2]), bo.z); a += gelu_exact(gx) * vn.z;
    gx = fmaf(d, bf2f(vv[3]), bo.w); a += gelu_exact(gx) * vn.w;
#pragma unroll
    for (int o = 32; o > 0; o >>= 1) a += __shfl_down(a, o, 64);
    __syncthreads();
    if ((t & 63) == 0) red[t >> 6] = a;
    __syncthreads();
    if (t == 0) out[row] = xeS[b] + c0 + red[0] + red[1] + red[2] + red[3];
  }
}

// ---------------------------------------------------------------------------
extern "C" void kernel_launch(void* const* d_in, const int* in_sizes, int n_in,
                              void* d_out, int out_size, void* d_ws,
                              size_t ws_size, hipStream_t stream) {
  const float* nt  = (const float*)d_in[0];
  const float* nn  = (const float*)d_in[1];
  const float* WQ  = (const float*)d_in[2];
  const float* bQ  = (const float*)d_in[3];
  const float* WK  = (const float*)d_in[4];
  const float* bK  = (const float*)d_in[5];
  const float* WV  = (const float*)d_in[6];
  const float* bV  = (const float*)d_in[7];
  const float* WO  = (const float*)d_in[8];
  const float* bO  = (const float*)d_in[9];
  const float* WE  = (const float*)d_in[10];
  const float* WEb = (const float*)d_in[11];
  const float* WN  = (const float*)d_in[12];
  const float* WNb = (const float*)d_in[13];
  const float* wa  = (const float*)d_in[14];
  const float* WAb = (const float*)d_in[15];
  float* out = (float*)d_out;

  char* w = (char*)d_ws;
  size_t o = 0;
  const size_t BIG = (size_t)M_TOT * 1024 * 2;          // 33.55 MB
  short* xn     = (short*)(w + o); o += BIG;
  short* vw     = (short*)(w + o); o += BIG;
  short* Bf     = (short*)(w + o); o += (size_t)2048 * 1024 * 2;  // [M1;M2]
  short* wqT    = (short*)(w + o); o += 2097152;
  short* wkT    = (short*)(w + o); o += 2097152;
  short* wvT    = (short*)(w + o); o += 2097152;
  short* wo_bf  = (short*)(w + o); o += 2097152;
  float* sPart  = (float*)(w + o); o += (size_t)M_TOT * 16 * 4;   // 1 MB
  float* xePart = (float*)(w + o); o += (size_t)M_TOT * 16 * 4;   // 1 MB
  float* bias2  = (float*)(w + o); o += 8192;           // [uQ(1024); bvw(1024)]
  float* vE     = (float*)(w + o); o += 4096;
  float* vN     = (float*)(w + o); o += 4096;
  float* uK     = (float*)(w + o); o += 4096;
  float* xk     = (float*)(w + o); o += 65536;
  float* c0     = (float*)(w + o); o += 256;
  float* c1     = (float*)(w + o); o += 256;
  (void)ws_size; (void)in_sizes; (void)n_in; (void)out_size;

  prep_w<<<2066, 256, 0, stream>>>(WQ, WK, WV, WO, WE, WN, wa, bQ, bK, bV,
                                   WEb, WNb, WAb, wqT, wkT, wvT, wo_bf,
                                   vE, vN, bias2, uK, c0, c1, bias2 + 1024);
  prep2<<<8320, 256, 0, stream>>>(wqT, wkT, wvT, wo_bf, Bf, Bf + 1048576,
                                  nn, uK, xn, xk);
  gemm_main<<<512, 512, 0, stream>>>(xn, Bf, bias2, nt, vE,
                                     sPart, xePart, vw);
  out2_kernel<<<N_SEQ, 256, 0, stream>>>(vw, sPart, xePart, xk, vN, bO,
                                         c0, c1, out);
}